// Round 12
// baseline (2397.959 us; speedup 1.0000x reference)
//
#include <hip/hip_runtime.h>
#include <math.h>

// ---- ws layout (u32/float offsets) ----
#define WS_CB2    0         // 192 (b_ih + b2.w_ih; +b_hh folded for r,z)
#define WS_QE1    192       // 16384
#define WS_XE1    16576     // 65536
#define WS_G      82112     // 65536
#define WS_HW     147648    // 266240 -> ends 413888
#define WS_FW1H   413888    // 2048 u32 (8 frags)
#define WS_FWIHH  415936    // 6144 u32 (24 frags)
#define WS_FW2M   422080    // 6144
#define WS_FWHH   428224    // 6144 -> ends 434368
#define WS_GFLAG  442560    // 64 x 16 u32 (64B-padded per-chain flags)

// ---- dynamic LDS (u32 offsets) ----
#define OW1H   0        // 2048
#define OWIH   2048     // 6144
#define OW2M   8192     // 6144
#define OSTG   14336    // [8][576]  staged h(t-1) f16 rows ([16][72] ushort)
#define OHF    18944    // [8][576]  own h f16 rows
#define OM1    23552    // [2][576]  m1 f16 rows
#define OGI    24704    // [4][12][128]  gi f16 tiles (uint2/lane)
#define OH32   30848    // [4][1024] h f32 rows (v11 swizzled layout)
#define OFLG   34944    // 0-3 fG, 4 fGiA, 5 fGiB, 6 fStage, 7 fC, 8 fM1a, 9 fM1b
#define LDSW   34960
#define LDSBYTES (LDSW*4)

typedef _Float16 f16x8 __attribute__((ext_vector_type(8)));
typedef float    f32x4 __attribute__((ext_vector_type(4)));
union U4H { uint4 u; f16x8 h; };
union U4F { uint4 u; f32x4 f; };
__device__ inline f16x8 TOH(uint4 u){ U4H z; z.u=u; return z.h; }
__device__ inline unsigned PKH(float a, float b){
  union{_Float16 h[2]; unsigned u;} z; z.h[0]=(_Float16)a; z.h[1]=(_Float16)b; return z.u;
}
__device__ inline float LOH(unsigned u){ union{unsigned x; _Float16 h[2];} z; z.x=u; return (float)z.h[0]; }
__device__ inline float HIH(unsigned u){ union{unsigned x; _Float16 h[2];} z; z.x=u; return (float)z.h[1]; }
#define MFMA(a,b,c) __builtin_amdgcn_mfma_f32_16x16x32_f16((a),(b),(c),0,0,0)
#define POLLGE(P,T) do{ while(*(volatile int*)(P) < (T)) {} asm volatile("" ::: "memory"); }while(0)
#define POLL4(P,T)  do{ volatile int* _f=(volatile int*)(P); \
  while(_f[0]<(T)||_f[1]<(T)||_f[2]<(T)||_f[3]<(T)){} asm volatile("" ::: "memory"); }while(0)
#define AL64(p)    __hip_atomic_load((p), __ATOMIC_RELAXED, __HIP_MEMORY_SCOPE_AGENT)
#define AS64(p,v)  __hip_atomic_store((p), (v), __ATOMIC_RELAXED, __HIP_MEMORY_SCOPE_AGENT)

// ================= precompute (v10/v11, verified) =================
__global__ __launch_bounds__(256) void kPrep(
    const int* __restrict__ q, const int* __restrict__ r,
    const float* __restrict__ x_emb, const float* __restrict__ q_emb,
    const float* __restrict__ init_h, const float* __restrict__ w1,
    const float* __restrict__ b1, const float* __restrict__ w2,
    const float* __restrict__ b2, const float* __restrict__ w_ih,
    const float* __restrict__ w_hh, const float* __restrict__ b_ih,
    const float* __restrict__ b_hh,
    float* __restrict__ ws, float* __restrict__ h_full)
{
  int idx = blockIdx.x*256 + threadIdx.x;
  unsigned* wsu = (unsigned*)ws;
  if (idx < 192) {
    int g = idx; float s = b_ih[g];
    for (int j=0;j<64;j++) s += b2[j]*w_ih[g*128+j];
    if (g < 128) s += b_hh[g];
    ws[WS_CB2+g] = s;
  } else if (idx < 16576) {
    int e = idx-192; int c = e>>6, i = e&63;
    float s = b1[i];
    for (int k=0;k<64;k++) s += q_emb[c*64+k]*w1[(64+k)*64+i];
    ws[WS_QE1+e] = s;
  } else if (idx < 82112) {
    int e = idx-16576; int bt = e>>6, i = e&63;
    int row = q[bt] + 256*r[bt];
    float s = b1[i];
    for (int k=0;k<64;k++) s += x_emb[row*64+k]*w1[(64+k)*64+i];
    ws[WS_XE1+e] = s;
  } else if (idx < 147648) {
    int e = idx-82112; int a = e>>8, cc = e&255;
    float s = 0.f;
    for (int d=0;d<64;d++) s += q_emb[a*64+d]*q_emb[cc*64+d];
    ws[WS_G+e] = s;
  } else if (idx < 409792) {
    int e = idx-147648; int bb = e>>14, cf = e&16383;
    h_full[(size_t)bb*65*16384 + cf] = init_h[cf];
  } else if (idx < 430272) {
    int e, tbl;
    if (idx < 411840)      { e = idx-409792; tbl=0; }
    else if (idx < 417984) { e = idx-411840; tbl=1; }
    else if (idx < 424128) { e = idx-417984; tbl=2; }
    else                   { e = idx-424128; tbl=3; }
    int f = e>>8, rem = e&255, lane = rem>>2, v = rem&3;
    int mt = f>>1, ks = f&1, li = lane&15, grp = lane>>4;
    int kg = ks*32 + grp*8 + v*2;
    float v0, v1;
    if (tbl==0){ int i = mt*16+li; v0 = w1[kg*64+i]; v1 = w1[(kg+1)*64+i];
      wsu[WS_FW1H+e] = PKH(v0,v1); }
    else if (tbl==1){ int g = mt*16+li; v0 = w_ih[g*128+64+kg]; v1 = w_ih[g*128+64+kg+1];
      wsu[WS_FWIHH+e] = PKH(v0,v1); }
    else if (tbl==2){ int g = mt*16+li; v0=0.f; v1=0.f;
      for (int j=0;j<64;j++){ float wij = w_ih[g*128+j];
        v0 += w2[kg*64+j]*wij; v1 += w2[(kg+1)*64+j]*wij; }
      wsu[WS_FW2M+e] = PKH(v0,v1); }
    else { int g = mt*16+li; v0 = w_hh[g*64+kg]; v1 = w_hh[g*64+kg+1];
      wsu[WS_FWHH+e] = PKH(v0,v1); }
  }
}

// ================= v12: split-gate MFMA wavefront =================
// 64 WGs (1 chain t), 448 threads (7 waves):
// w=0..3: G-waves (tile m: 6 whh MFMA + gates for 4 outputs/lane)
// w=4,5:  WH-waves (gi precompute, mt-pairs, runs ahead; tables in LDS)
// w=6:    IO wave (staging + coalesced copyout + cross-WG flags)
__global__ __launch_bounds__(448,1) void kW(
    const int* __restrict__ q, const float* __restrict__ b_hh,
    const float* __restrict__ init_h,
    float* __restrict__ ws, float* __restrict__ h_full)
{
  extern __shared__ unsigned lds[];
  const int bid = blockIdx.x;
  const int t = ((bid&7)<<3) | (bid>>3);
  const int tid = threadIdx.x, w = tid>>6, lane = tid&63;
  const int b = lane&15, grp = lane>>4;
  unsigned* wsu = (unsigned*)ws;
  unsigned* gflag = wsu + WS_GFLAG;
  int* FLG = (int*)&lds[OFLG];
  ushort* lds16 = (ushort*)lds;

  for (int k=tid; k<2048; k+=448) lds[OW1H+k] = wsu[WS_FW1H+k];
  for (int k=tid; k<6144; k+=448) lds[OWIH+k] = wsu[WS_FWIHH+k];
  for (int k=tid; k<6144; k+=448) lds[OW2M+k] = wsu[WS_FW2M+k];
  for (int k=tid; k<4608; k+=448) lds[OHF+k] = 0;      // h(-1)=0 (slot 7)
  if (tid<10) FLG[tid]=0;
  __syncthreads();

  if (w < 4) {
    // ---------------- G-wave m: critical GRU tile ----------------
    const int m = w;
    const uint4* whhg = (const uint4*)(wsu + WS_FWHH);
    float bhv[4];
    #pragma unroll
    for (int e=0;e<4;e++) bhv[e] = b_hh[128 + m*16 + grp*4 + e];
    f32x4 hv = (f32x4){0.f,0.f,0.f,0.f};
    for (int c=0;c<256;c++){
      POLL4(&FLG[0], c);                  // all waves finished cell c-1
      POLLGE(&FLG[4], c+1);               // gi[c] ready (WH_a)
      POLLGE(&FLG[5], c+1);               // gi[c] ready (WH_b)
      POLLGE(&FLG[7], c-3);               // h32 ring free (IO)
      const ushort* hfp = lds16 + (OHF*2) + ((c+7)&7)*1152;
      f16x8 hb0 = TOH(*(const uint4*)&hfp[b*72 + grp*8]);
      f16x8 hb1 = TOH(*(const uint4*)&hfp[b*72 + 32 + grp*8]);
      f32x4 ar = (f32x4){0.f,0.f,0.f,0.f}, az = ar, an = ar;
      ar = MFMA(TOH(whhg[(2*m)*64+lane]),     hb0, ar);
      ar = MFMA(TOH(whhg[(2*m+1)*64+lane]),   hb1, ar);
      az = MFMA(TOH(whhg[(2*(4+m))*64+lane]), hb0, az);
      az = MFMA(TOH(whhg[(2*(4+m)+1)*64+lane]),hb1, az);
      an = MFMA(TOH(whhg[(2*(8+m))*64+lane]), hb0, an);
      an = MFMA(TOH(whhg[(2*(8+m)+1)*64+lane]),hb1, an);
      const unsigned* gbase = lds + OGI + (c&3)*1536;
      uint2 gru = *(const uint2*)&gbase[(m)*128 + lane*2];
      uint2 gzu = *(const uint2*)&gbase[(4+m)*128 + lane*2];
      uint2 gnu = *(const uint2*)&gbase[(8+m)*128 + lane*2];
      float grv[4] = {LOH(gru.x),HIH(gru.x),LOH(gru.y),HIH(gru.y)};
      float gzv[4] = {LOH(gzu.x),HIH(gzu.x),LOH(gzu.y),HIH(gzu.y)};
      float gnv[4] = {LOH(gnu.x),HIH(gnu.x),LOH(gnu.y),HIH(gnu.y)};
      f32x4 h4 = hv;
      #pragma unroll
      for (int e=0;e<4;e++){
        float rg = 1.f/(1.f+__expf(-(grv[e]+ar[e])));
        float zg = 1.f/(1.f+__expf(-(gzv[e]+az[e])));
        float xn = gnv[e] + rg*(an[e]+bhv[e]);
        float e2 = __expf(2.f*xn);
        float ng = 1.f - 2.f/(e2+1.f);
        h4[e] = zg*h4[e] + (1.f-zg)*ng;
      }
      hv = h4;
      ushort* hop = lds16 + (OHF*2) + (c&7)*1152;
      *(uint2*)&hop[b*72 + m*16 + grp*4] = make_uint2(PKH(h4[0],h4[1]), PKH(h4[2],h4[3]));
      U4F hw_; hw_.f = h4;
      uint4* h32p = (uint4*)&lds[OH32 + (c&3)*1024];
      int idx = m*64 + grp*16 + b;
      h32p[idx ^ ((idx>>4)&7)] = hw_.u;
      asm volatile("s_waitcnt lgkmcnt(0)" ::: "memory");
      if (lane==0) *(volatile int*)&FLG[m] = c+1;
    }
  } else if (w < 6) {
    // ---------------- WH-wave: gi precompute ----------------
    const int p = w-4;
    const int mtA = p*2, mtB = mtA+1;
    const int TL[6] = {mtA, mtB, 4+mtA, 4+mtB, 8+mtA, 8+mtB};
    const uint4* w1L = (const uint4*)&lds[OW1H];
    const uint4* wiL = (const uint4*)&lds[OWIH];
    const uint4* w2L = (const uint4*)&lds[OW2M];
    const int qv = q[b*64+t];
    f32x4 xrA, xrB;
    #pragma unroll
    for (int e=0;e<4;e++){
      xrA[e] = ws[WS_XE1 + (b*64+t)*64 + mtA*16 + grp*4 + e];
      xrB[e] = ws[WS_XE1 + (b*64+t)*64 + mtB*16 + grp*4 + e];
    }
    ushort* stg16 = (ushort*)lds + OSTG*2;
    ushort* m116  = (ushort*)lds + OM1*2;
    for (int s=0;s<256;s++){
      POLLGE(&FLG[6], s+1);               // row staged
      POLL4(&FLG[0], s-3);                // gi ring depth 4
      POLLGE(&FLG[5-p], s-1);             // partner consumed m1[s-2]
      const ushort* sp16 = stg16 + (s&7)*1152;
      f16x8 sb0 = TOH(*(const uint4*)&sp16[b*72 + grp*8]);
      f16x8 sb1 = TOH(*(const uint4*)&sp16[b*72 + 32 + grp*8]);
      ushort* mrow = m116 + (s&1)*1152;
      {
        f32x4 a = (f32x4){0.f,0.f,0.f,0.f};
        a = MFMA(TOH(w1L[(2*mtA)*64+lane]), sb0, a);
        a = MFMA(TOH(w1L[(2*mtA+1)*64+lane]), sb1, a);
        f32x4 ev = (qv==s)? xrA : *(const f32x4*)&ws[WS_QE1 + s*64 + mtA*16 + grp*4];
        *(uint2*)&mrow[b*72 + mtA*16 + grp*4] =
          make_uint2(PKH(fmaxf(a[0]+ev[0],0.f),fmaxf(a[1]+ev[1],0.f)),
                     PKH(fmaxf(a[2]+ev[2],0.f),fmaxf(a[3]+ev[3],0.f)));
      }
      {
        f32x4 a = (f32x4){0.f,0.f,0.f,0.f};
        a = MFMA(TOH(w1L[(2*mtB)*64+lane]), sb0, a);
        a = MFMA(TOH(w1L[(2*mtB+1)*64+lane]), sb1, a);
        f32x4 ev = (qv==s)? xrB : *(const f32x4*)&ws[WS_QE1 + s*64 + mtB*16 + grp*4];
        *(uint2*)&mrow[b*72 + mtB*16 + grp*4] =
          make_uint2(PKH(fmaxf(a[0]+ev[0],0.f),fmaxf(a[1]+ev[1],0.f)),
                     PKH(fmaxf(a[2]+ev[2],0.f),fmaxf(a[3]+ev[3],0.f)));
      }
      asm volatile("s_waitcnt lgkmcnt(0)" ::: "memory");
      if (lane==0) *(volatile int*)&FLG[8+p] = s+1;
      POLLGE(&FLG[9-p], s+1);             // partner m1 half written
      f16x8 mb0 = TOH(*(const uint4*)&mrow[b*72 + grp*8]);
      f16x8 mb1 = TOH(*(const uint4*)&mrow[b*72 + 32 + grp*8]);
      #pragma unroll
      for (int ti=0; ti<6; ti++){
        int T = TL[ti];
        f32x4 a = *(const f32x4*)&ws[WS_CB2 + T*16 + grp*4];
        a = MFMA(TOH(wiL[(2*T)*64+lane]),   sb0, a);
        a = MFMA(TOH(wiL[(2*T+1)*64+lane]), sb1, a);
        a = MFMA(TOH(w2L[(2*T)*64+lane]),   mb0, a);
        a = MFMA(TOH(w2L[(2*T+1)*64+lane]), mb1, a);
        *(uint2*)&lds[OGI + (s&3)*1536 + T*128 + lane*2] =
          make_uint2(PKH(a[0],a[1]), PKH(a[2],a[3]));
      }
      asm volatile("s_waitcnt lgkmcnt(0)" ::: "memory");
      if (lane==0) *(volatile int*)&FLG[4+p] = s+1;
    }
  } else {
    // ---------------- IO wave ----------------
    unsigned* gfp = gflag + (t-1)*16;
    unsigned* gfc = gflag + t*16;
    unsigned long long* hf64 = (unsigned long long*)h_full;
    const int l31 = lane&31, hw_ = lane>>5;
    const int c_mt = l31>>3, c_gp = (l31>>1)&3, c_e = 2*(l31&1), c_swz = (l31>>1)&7;
    unsigned gv = 0; int sp = 0;
    for (int c=0;c<256;c++){
      int lim = c+4; if (lim>255) lim=255;
      while (sp <= lim){
        POLLGE(&FLG[4], sp-7);            // stg ring depth 8
        POLLGE(&FLG[5], sp-7);
        if (t>0){
          while (gv < (unsigned)(sp+1)){
            gv = AL64(gfp);
            if (gv < (unsigned)(sp+1)) __builtin_amdgcn_s_sleep(1);
          }
        }
        #pragma unroll
        for (int k=0;k<8;k++){
          int bb = 2*k + hw_;
          int j = 2*l31;
          float f0, f1;
          if (t==0){ f0 = init_h[sp*64+j]; f1 = init_h[sp*64+j+1]; }
          else {
            unsigned long long v = AL64(&hf64[(((size_t)(bb*65+t)<<14) + sp*64 + j)>>1]);
            union{unsigned long long q_; float f[2];} cv; cv.q_ = v;
            f0 = cv.f[0]; f1 = cv.f[1];
          }
          lds[OSTG + (sp&7)*576 + bb*36 + l31] = PKH(f0,f1);
        }
        asm volatile("s_waitcnt lgkmcnt(0)" ::: "memory");
        if (lane==0) *(volatile int*)&FLG[6] = sp+1;
        sp++;
      }
      POLL4(&FLG[0], c+1);                // row c complete
      unsigned long long vals[8];
      #pragma unroll
      for (int k=0;k<8;k++){
        int bb = 2*k + hw_;
        int idx = c_mt*64 + c_gp*16 + bb;
        vals[k] = *(const unsigned long long*)&lds[OH32 + (c&3)*1024 + (idx ^ c_swz)*4 + c_e];
      }
      asm volatile("s_waitcnt lgkmcnt(0)" ::: "memory");
      if (lane==0) *(volatile int*)&FLG[7] = c+1;
      #pragma unroll
      for (int k=0;k<8;k++){
        int bb = 2*k + hw_;
        AS64(&hf64[(((size_t)(bb*65+t+1)<<14) + c*64 + 2*l31)>>1], vals[k]);
      }
      if ((c&1)==1){
        asm volatile("s_waitcnt vmcnt(0)" ::: "memory");
        if (lane==0) AS64(gfc, (unsigned)(c+1));
      }
    }
  }
}

// ================= hw[b][u][c] = h_full[b][u][c][:] . out_w =================
__global__ __launch_bounds__(256) void kHw(const float* __restrict__ h_full,
    const float* __restrict__ out_w, float* __restrict__ hw)
{
  __shared__ float ow[64];
  if (threadIdx.x < 64) ow[threadIdx.x] = out_w[threadIdx.x];
  __syncthreads();
  const int blk = blockIdx.x, c = threadIdx.x;
  const float* hp = h_full + ((size_t)blk*256 + c)*64;
  float s = 0.f;
  #pragma unroll
  for (int f=0; f<64; f++) s += hp[f]*ow[f];
  hw[blk*256+c] = s;
}

// ================= readout =================
__global__ __launch_bounds__(256) void kY(const int* __restrict__ q,
    const float* __restrict__ ws, const float* __restrict__ bias,
    const float* __restrict__ theta, float* __restrict__ y)
{
  const float* G  = ws + WS_G;
  const float* hw = ws + WS_HW;
  const int b = blockIdx.x >> 2, tq = blockIdx.x & 3;
  const int c = threadIdx.x;
  __shared__ float siml[64][256];
  for (int u=0; u<64; u++) {
    int qq = q[b*64+u];
    siml[u][c] = G[qq*256+c];
  }
  __syncthreads();
  const float rate = __expf(theta[0]);
  const float bv = bias[c];
  const float* hwb = hw + b*65*256;
  for (int tt=0; tt<16; tt++) {
    const int t = tq*16+tt;
    float mx = -1e30f;
    for (int u=0; u<=t; u++) {
      float s = __expf(-rate*(float)(t-u))*siml[u][c];
      mx = fmaxf(mx, s);
    }
    float se = 0.f, sw = 0.f;
    for (int u=0; u<=t; u++) {
      float s = __expf(-rate*(float)(t-u))*siml[u][c];
      float e = __expf(s-mx);
      se += e; sw += e*hwb[u*256+c];
    }
    float lg = hwb[(t+1)*256+c] + sw/se + bv;
    y[(b*64+t)*256+c] = 1.f/(1.f+__expf(-lg));
  }
}

extern "C" void kernel_launch(void* const* d_in, const int* in_sizes, int n_in,
                              void* d_out, int out_size, void* d_ws, size_t ws_size,
                              hipStream_t stream)
{
  (void)in_sizes; (void)n_in; (void)out_size; (void)ws_size;
  const int*   q      = (const int*)  d_in[0];
  const int*   r      = (const int*)  d_in[1];
  const float* x_emb  = (const float*)d_in[2];
  const float* q_emb  = (const float*)d_in[3];
  const float* init_h = (const float*)d_in[4];
  const float* w1     = (const float*)d_in[5];
  const float* b1     = (const float*)d_in[6];
  const float* w2     = (const float*)d_in[7];
  const float* b2     = (const float*)d_in[8];
  const float* w_ih   = (const float*)d_in[9];
  const float* w_hh   = (const float*)d_in[10];
  const float* b_ih   = (const float*)d_in[11];
  const float* b_hh   = (const float*)d_in[12];
  const float* bias   = (const float*)d_in[13];
  const float* out_w  = (const float*)d_in[14];
  const float* theta  = (const float*)d_in[15];

  float* out    = (float*)d_out;
  float* y      = out;
  float* h_full = out + 262144;
  float* ws     = (float*)d_ws;

  hipMemsetAsync((unsigned*)ws + WS_GFLAG, 0, 64*16*sizeof(unsigned), stream);
  kPrep<<<1681,256,0,stream>>>(q,r,x_emb,q_emb,init_h,w1,b1,w2,b2,w_ih,w_hh,b_ih,b_hh,ws,h_full);
  {
    hipFuncSetAttribute((const void*)kW, hipFuncAttributeMaxDynamicSharedMemorySize, LDSBYTES);
    void* ka[] = { (void*)&q, (void*)&b_hh, (void*)&init_h, (void*)&ws, (void*)&h_full };
    hipError_t e = hipLaunchCooperativeKernel((const void*)kW, dim3(64), dim3(448), ka, LDSBYTES, stream);
    if (e != hipSuccess) {
      kW<<<dim3(64),dim3(448),LDSBYTES,stream>>>(q,b_hh,init_h,ws,h_full);
    }
  }
  kHw<<<1040,256,0,stream>>>(h_full, out_w, ws + WS_HW);
  kY<<<64,256,0,stream>>>(q, ws, bias, theta, y);
}